// Round 3
// baseline (149.568 us; speedup 1.0000x reference)
//
#include <hip/hip_runtime.h>

// N=524288, D=9, E=2, H=128, M=32, O=2, K=1.
// LAYOUT (confirmed R6): d_in fp32, d_out FP32 (N*2 outputs + 1 loss).
// NUMERICS: pure fp32 everywhere; accumulation order must stay bit-identical
// to the accepted kernel (bf16-compare space: one flipped large output costs
// absmax ~0.68 > threshold). All fmaf chains below preserve that order.
//
// R3: 1 token/thread (grid 2048 -> 100% occupancy cap; R2's 2-token layout
// capped at 50% and measured 27.6%, with true VALU issue only ~25% of dur —
// rocprof VALUBusy is ~2x-inflated on gfx950, gfx94x formula). R1's 1-token
// failure modes fixed: no threadfence (R1 stall suspect), and the fast path
// processes j IN PAIRS -> two independent 9-FMA chains (ILP-2) with tail
// FMAs applied in strict j order (bit-exact). Boundary wave keeps R0's
// proven dense-both body. prep's serial 72-iter dtype probe parallelized.
#define NTOK 524288
#define TPB  256
#define NBLK (NTOK / TPB)   // 2048

__device__ __forceinline__ float bf2f(unsigned short u) {
    union { unsigned int i; float f; } v;
    v.i = ((unsigned int)u) << 16;
    return v.f;
}

// input load: raw fp32 (bf16-buffer fallback kept purely as safety)
__device__ __forceinline__ float ldq(const void* p, int i, bool f32) {
    if (f32) return ((const float*)p)[i];
    return bf2f(((const unsigned short*)p)[i]);
}

// ---------------------------------------------------------------------------
// Prep: detect buffer dtype (parallel probe), zero counter, stage w_gate,
// fold W2@Wout (+ b2@Wout + bout), pack per-hidden-unit weights.
// wpack layout (expert-major): wpack[e*1536 + j*12 + {0..8:W1col, 9:b1,
// 10..11:W2'}] — 48B records, 16B-aligned.
// ---------------------------------------------------------------------------
__global__ void prep_kernel(const void* __restrict__ num_prop,
                            const void* __restrict__ wgate,
                            const void* __restrict__ W1,
                            const void* __restrict__ b1,
                            const void* __restrict__ W2,
                            const void* __restrict__ b2,
                            const void* __restrict__ Wout,
                            const void* __restrict__ bout,
                            unsigned int* __restrict__ cnt1,
                            int* __restrict__ flag,
                            float* __restrict__ bpp,
                            float* __restrict__ wgf,
                            float* __restrict__ wpack)
{
    __shared__ unsigned int bad;
    __shared__ int sflag;
    const int t = threadIdx.x;
    if (t == 0) { bad = 0u; *cnt1 = 0u; }
    __syncthreads();
    if (t < 72) {   // parallel dtype probe (was a serial 72-iter loop)
        const unsigned short* u = (const unsigned short*)num_prop;
        int e = (u[t] >> 7) & 0xFF;
        if (e < 64 || e > 191) atomicOr(&bad, 1u);
    }
    __syncthreads();
    if (t == 0) { sflag = (int)bad; *flag = (int)bad; }
    __syncthreads();
    const bool f32 = (sflag != 0);

    if (t < 18) wgf[t] = ldq(wgate, t, f32);        // w_gate [9,2] raw fp32

    if (t < 4) {  // b''[e][o] = sum_m b2[e][m]*Wout[m][o] + bout[o]
        int e = t >> 1, o = t & 1;
        float acc = ldq(bout, o, f32);
        for (int m = 0; m < 32; ++m)
            acc += ldq(b2, e * 32 + m, f32) * ldq(Wout, m * 2 + o, f32);
        bpp[t] = acc;
    }

    const int e = t >> 7;       // 256 threads -> (e, j)
    const int j = t & 127;
    float p0 = 0.f, p1 = 0.f;
    for (int m = 0; m < 32; ++m) {
        float w = ldq(W2, (e * 128 + j) * 32 + m, f32);
        p0 += w * ldq(Wout, m * 2 + 0, f32);
        p1 += w * ldq(Wout, m * 2 + 1, f32);
    }
    float* dst = wpack + e * 1536 + j * 12;
    #pragma unroll
    for (int d = 0; d < 9; ++d)
        dst[d] = ldq(W1, (e * 9 + d) * 128 + j, f32);
    dst[9]  = ldq(b1, e * 128 + j, f32);
    dst[10] = p0;
    dst[11] = p1;
}

// ---------------------------------------------------------------------------
// Main: 256 tokens/block, 1/thread. Stage x -> LDS, gate, stable partition
// by expert (ballot+prefix, smap: slot -> token). Expert-uniform waves run
// the single-expert loop over j-PAIRS: two independent 9-FMA chains per
// iteration (ILP-2), tail FMAs in strict j order (bit-exact vs accepted
// kernel). Boundary wave (<=1/4) runs R0's dense-both body. Results bounce
// through LDS to token order -> coalesced float2 stores.
// ---------------------------------------------------------------------------
__global__ __launch_bounds__(TPB, 8)
void moe_main(const void* __restrict__ xg,
              const int* __restrict__ flag,
              const float* __restrict__ wgf,
              const float* __restrict__ bpp,
              const float* __restrict__ wpack,
              unsigned int* __restrict__ cnt1,
              float2* __restrict__ out)
{
    __shared__ __align__(16) float xs[TPB * 9];    // 9216 B
    __shared__ unsigned char smap[TPB];
    __shared__ unsigned int wcnt[4];

    const int tid  = threadIdx.x;
    const int lane = tid & 63;
    const int wave = tid >> 6;

    const bool f32 = (*flag) != 0;
    const int gbase = blockIdx.x * (TPB * 9);
    if (f32) {
        const float* xf = (const float*)xg;
        #pragma unroll
        for (int i = 0; i < 9; ++i)
            xs[tid + i * TPB] = xf[gbase + tid + i * TPB];   // RAW fp32
    } else {
        const unsigned short* xu = (const unsigned short*)xg;
        for (int i = tid; i < TPB * 9; i += TPB)
            xs[i] = bf2f(xu[gbase + i]);
    }
    __syncthreads();

    // --- gate for own token (same fmaf chain as accepted kernel) ---
    float l0 = 0.f, l1 = 0.f;
    #pragma unroll
    for (int d = 0; d < 9; ++d) {
        float xv = xs[tid * 9 + d];
        l0 = fmaf(xv, wgf[d * 2 + 0], l0);
        l1 = fmaf(xv, wgf[d * 2 + 1], l1);
    }
    const bool e1 = l1 > l0;   // tie -> expert 0 (stable top_k)

    // --- stable partition: expert-0 tokens to slots [0,n0), expert-1 after ---
    unsigned long long bal = __ballot(e1);
    if (lane == 0) wcnt[wave] = (unsigned int)__popcll(bal);
    __syncthreads();
    int pre = 0, tot = 0;
    #pragma unroll
    for (int w = 0; w < 4; ++w) {
        int c = (int)wcnt[w];
        if (w < wave) pre += c;
        tot += c;
    }
    const int n1 = tot;
    const int n0 = TPB - n1;
    const int p1 = pre + (int)__popcll(bal & ((1ull << lane) - 1ull));
    const int slot = e1 ? (n0 + p1) : (tid - p1);
    smap[slot] = (unsigned char)tid;
    if (tid == 0) atomicAdd(cnt1, (unsigned int)n1);
    __syncthreads();

    // --- this thread now processes slot `tid` ---
    const int t = (int)smap[tid];
    float x[9];
    #pragma unroll
    for (int d = 0; d < 9; ++d) x[d] = xs[t * 9 + d];

    // scalarize the uniformity test so the fast path keeps s_load weights
    const int wbase = __builtin_amdgcn_readfirstlane(tid) & 192;  // wave*64
    const int n0u   = __builtin_amdgcn_readfirstlane(n0);

    float2 res;
    if (n0u <= wbase || n0u >= wbase + 64) {
        // expert-uniform wave: j-pairs, two independent h-chains (ILP-2),
        // tail FMAs strictly in j order -> bit-identical accumulation.
        const int ew = (n0u <= wbase) ? 1 : 0;
        const float* wp = wpack + ew * 1536;
        float a0 = bpp[ew * 2 + 0], a1 = bpp[ew * 2 + 1];
        #pragma unroll 2
        for (int jp = 0; jp < 64; ++jp) {
            const float* r0 = wp + jp * 24;   // record 2*jp   (uniform -> s_load)
            const float* r1 = r0 + 12;        // record 2*jp+1
            float h0 = r0[9], h1 = r1[9];
            #pragma unroll
            for (int d = 0; d < 9; ++d) {
                h0 = fmaf(x[d], r0[d], h0);
                h1 = fmaf(x[d], r1[d], h1);
            }
            h0 = fmaxf(h0, 0.f);
            h1 = fmaxf(h1, 0.f);
            a0 = fmaf(h0, r0[10], a0); a1 = fmaf(h0, r0[11], a1);  // j = 2*jp
            a0 = fmaf(h1, r1[10], a0); a1 = fmaf(h1, r1[11], a1);  // j = 2*jp+1
        }
        res.x = a0; res.y = a1;
    } else {
        // boundary wave (<=1/block): R0's dense-both body, select per token
        const bool em = (tid >= n0u);
        float a00 = bpp[0], a01 = bpp[1], a10 = bpp[2], a11 = bpp[3];
        #pragma unroll 4
        for (int j = 0; j < 128; ++j) {
            const float* r0 = wpack + j * 12;
            const float* r1 = wpack + 1536 + j * 12;
            float h0 = r0[9], h1 = r1[9];
            #pragma unroll
            for (int d = 0; d < 9; ++d) {
                h0 = fmaf(x[d], r0[d], h0);
                h1 = fmaf(x[d], r1[d], h1);
            }
            h0 = fmaxf(h0, 0.f);
            h1 = fmaxf(h1, 0.f);
            a00 = fmaf(h0, r0[10], a00); a01 = fmaf(h0, r0[11], a01);
            a10 = fmaf(h1, r1[10], a10); a11 = fmaf(h1, r1[11], a11);
        }
        res.x = em ? a10 : a00;
        res.y = em ? a11 : a01;
    }

    // --- bounce through LDS to restore token order; coalesced stores ---
    __syncthreads();                        // all xs reads complete
    ((float2*)xs)[t] = res;
    __syncthreads();
    out[blockIdx.x * TPB + tid] = ((float2*)xs)[tid];
}

// Loss: gates one-hot value-1.0 -> importance == load == counts.
// cv^2 ddof=1: var=(c0-c1)^2/2, mean=N/2; loss = 0.01*2*cv^2 (~1e-9).
__global__ void finalize_kernel(const unsigned int* __restrict__ cnt1,
                                float* __restrict__ loss_out)
{
    double c1 = (double)(*cnt1);
    double c0 = (double)NTOK - c1;
    double diff = c0 - c1;
    double mean = (double)NTOK * 0.5;
    double var  = 0.5 * diff * diff;
    double cv2  = var / (mean * mean + 1e-10);
    *loss_out = (float)(0.02 * cv2);
}

extern "C" void kernel_launch(void* const* d_in, const int* in_sizes, int n_in,
                              void* d_out, int out_size, void* d_ws, size_t ws_size,
                              hipStream_t stream) {
    const void* num_prop = d_in[0]; // [N,9] fp32
    // d_in[1] = cat_prop (unused)
    const void* w_gate   = d_in[2]; // [9,2]
    const void* W1       = d_in[3]; // [2,9,128]
    const void* b1       = d_in[4]; // [2,128]
    const void* W2       = d_in[5]; // [2,128,32]
    const void* b2       = d_in[6]; // [2,32]
    const void* Wout     = d_in[7]; // [32,2]
    const void* bout     = d_in[8]; // [2]
    // d_in[9] = k (==1)

    char* ws = (char*)d_ws;
    unsigned int* cnt1 = (unsigned int*)ws;          // @0
    int* flag          = (int*)(ws + 8);             // @8
    float* bpp         = (float*)(ws + 16);          // 4 f
    float* wgf         = (float*)(ws + 64);          // 18 f
    float* wpack       = (float*)(ws + 192);         // 3072 f (expert-major)

    float*  outf = (float*)d_out;                    // FP32: N*2 + loss
    float2* out2 = (float2*)d_out;

    hipLaunchKernelGGL(prep_kernel, dim3(1), dim3(256), 0, stream,
                       num_prop, w_gate, W1, b1, W2, b2, Wout, bout,
                       cnt1, flag, bpp, wgf, wpack);
    hipLaunchKernelGGL(moe_main, dim3(NBLK), dim3(TPB), 0, stream,
                       num_prop, flag, wgf, bpp, wpack, cnt1, out2);
    hipLaunchKernelGGL(finalize_kernel, dim3(1), dim3(1), 0, stream,
                       cnt1, outf + (size_t)NTOK * 2);
}